// Round 11
// baseline (347.009 us; speedup 1.0000x reference)
//
#include <hip/hip_runtime.h>
#include <hip/hip_bf16.h>
#include <math.h>

#define B 32
#define S 1024
#define IN_DIM 16
#define E 128
#define NH 4
#define DH 32
#define HDIM 256
#define ROWS (B*S)   /* 32768 */
#define EPS 1e-5f

#define N_IPW (3*384*128)
#define N_SQ  (3*128*128)
#define NCVT ((N_IPW + 3*N_SQ) / 256)   /* 1152 cvt blocks */

typedef __bf16 bf16x8 __attribute__((ext_vector_type(8)));
typedef __bf16 bf16x4 __attribute__((ext_vector_type(4)));
typedef __bf16 bf16x2 __attribute__((ext_vector_type(2)));
typedef float f32x4 __attribute__((ext_vector_type(4)));

union BF2U { bf16x2 b; unsigned int u; };
__device__ inline unsigned int pk2(float a, float b) {
    BF2U x; x.b[0] = (__bf16)a; x.b[1] = (__bf16)b; return x.u;
}

// 16B logical access as two 8B LDS ops (rows padded to RP%8==4 elems are only
// 8B-aligned; RP%8==4 makes every hot pattern exactly 4 dwords/bank).
union U8 { bf16x8 v8; bf16x4 v4[2]; };
__device__ inline void st8(__bf16* p, bf16x8 v) {
    U8 u; u.v8 = v;
    *(bf16x4*)p = u.v4[0];
    *(bf16x4*)(p + 4) = u.v4[1];
}
__device__ inline bf16x8 ld8(const __bf16* p) {
    U8 u;
    u.v4[0] = *(const bf16x4*)p;
    u.v4[1] = *(const bf16x4*)(p + 4);
    return u.v8;
}

// ---------------- fused weight-cvt + embed ----------------
__global__ __launch_bounds__(256) void k_embedcvt(
        const float* __restrict__ ipw, const float* __restrict__ ow,
        const float* __restrict__ w1, const float* __restrict__ w2,
        __bf16* __restrict__ wbo,
        const float* __restrict__ x, const float* __restrict__ W,
        const float* __restrict__ bias, __bf16* __restrict__ hb)
{
    int t = threadIdx.x;
    if (blockIdx.x < NCVT) {
        int i = blockIdx.x * 256 + t;
        float v;
        if (i < N_IPW) v = ipw[i];
        else if (i < N_IPW + N_SQ) v = ow[i - N_IPW];
        else if (i < N_IPW + 2 * N_SQ) v = w1[i - N_IPW - N_SQ];
        else v = w2[i - N_IPW - 2 * N_SQ];
        wbo[i] = (__bf16)v;
        return;
    }
    int row0 = (blockIdx.x - NCVT) * 16;
    __shared__ float xs[16][16];
    xs[t >> 4][t & 15] = x[(row0 + (t >> 4)) * IN_DIM + (t & 15)];
    __syncthreads();
    int sub = t >> 7, tc = t & 127;
    float w[16];
#pragma unroll
    for (int i = 0; i < 16; ++i) w[i] = W[tc * 16 + i];
    float bb = bias[tc];
#pragma unroll
    for (int rr = 0; rr < 8; ++rr) {
        int lr = sub * 8 + rr;
        float acc = bb;
#pragma unroll
        for (int i = 0; i < 16; ++i) acc += xs[lr][i] * w[i];
        hb[(size_t)(row0 + lr) * E + tc] = (__bf16)fmaxf(acc, 0.f);
    }
}

// ---------------- QKV GEMM (staged): qk[rows][256] + vt[b,h,d,s] ----------------
__global__ __launch_bounds__(256) void k_gemm_qkv(const __bf16* __restrict__ A,
        const __bf16* __restrict__ W, const float* __restrict__ bias,
        __bf16* __restrict__ qk, __bf16* __restrict__ vt)
{
    __shared__ __attribute__((aligned(16))) __bf16 As[128][132];
    __shared__ __attribute__((aligned(16))) __bf16 Ws[64][132];
    int t = threadIdx.x;
    int m0 = blockIdx.y * 128, n0 = blockIdx.x * 64;
    {
        int arow = t >> 1, acol = (t & 1) * 64;
        const __bf16* Ap = A + (size_t)(m0 + arow) * 128 + acol;
#pragma unroll
        for (int j = 0; j < 8; ++j)
            st8(&As[arow][acol + j * 8], *(const bf16x8*)&Ap[j * 8]);
        int wrow = t >> 2, wcol = (t & 3) * 32;
        const __bf16* Wp = W + (size_t)(n0 + wrow) * 128 + wcol;
#pragma unroll
        for (int j = 0; j < 4; ++j)
            st8(&Ws[wrow][wcol + j * 8], *(const bf16x8*)&Wp[j * 8]);
    }
    __syncthreads();
    int lane = t & 63, wv = t >> 6;
    int l15 = lane & 15, quad = lane >> 4;
    int wm = (wv & 1) * 64, wn = (wv >> 1) * 32;
    f32x4 acc[2][4];
#pragma unroll
    for (int i = 0; i < 2; ++i)
#pragma unroll
        for (int j = 0; j < 4; ++j) acc[i][j] = (f32x4){0.f, 0.f, 0.f, 0.f};
#pragma unroll
    for (int kc = 0; kc < 4; ++kc) {
        bf16x8 aw[2], ba[4];
#pragma unroll
        for (int nc = 0; nc < 2; ++nc)
            aw[nc] = ld8(&Ws[wn + nc * 16 + l15][kc * 32 + quad * 8]);
#pragma unroll
        for (int mc = 0; mc < 4; ++mc)
            ba[mc] = ld8(&As[wm + mc * 16 + l15][kc * 32 + quad * 8]);
#pragma unroll
        for (int nc = 0; nc < 2; ++nc)
#pragma unroll
            for (int mc = 0; mc < 4; ++mc)
                acc[nc][mc] = __builtin_amdgcn_mfma_f32_16x16x32_bf16(aw[nc], ba[mc], acc[nc][mc], 0, 0, 0);
    }
#pragma unroll
    for (int nc = 0; nc < 2; ++nc) {
        float4 bv = *(const float4*)&bias[n0 + wn + nc * 16 + quad * 4];
#pragma unroll
        for (int mc = 0; mc < 4; ++mc) {
            float v0 = acc[nc][mc][0] + bv.x;
            float v1 = acc[nc][mc][1] + bv.y;
            float v2 = acc[nc][mc][2] + bv.z;
            float v3 = acc[nc][mc][3] + bv.w;
            int n = n0 + wn + nc * 16 + quad * 4;
            int m = m0 + wm + mc * 16 + l15;
            if (n < 256) {
                uint2 u; u.x = pk2(v0, v1); u.y = pk2(v2, v3);
                *(uint2*)&qk[(size_t)m * 256 + n] = u;
            } else {
                int dp = n - 256;
                int hq = dp >> 5, d0 = dp & 31;
                __bf16* vp = vt + (((size_t)(m >> 10) * 4 + hq) * 32 + d0) * 1024 + (m & 1023);
                vp[0] = (__bf16)v0; vp[1024] = (__bf16)v1;
                vp[2048] = (__bf16)v2; vp[3072] = (__bf16)v3;
            }
        }
    }
}

// ---------------- MFMA flash attention v5 ----------------
// v4's Schraudolph exp2 + ones-MFMA row-sum kept, but q-tile back to 64
// (1 q-group/wave): grid 2048 blocks, LDS 26.6 KB -> 6 blocks/CU = 24
// waves/CU (was 16). Occupancy is the lever: both pipes were <50% at q128
// (latency-bound); the per-iter dependent chain also halves.
__global__ __launch_bounds__(256) void k_attn5(const __bf16* __restrict__ qk,
        const __bf16* __restrict__ vt, __bf16* __restrict__ O)
{
    int qt = blockIdx.x & 15, bh = blockIdx.x >> 4;
    int hh = bh & 3, b = bh >> 2;
    __shared__ __attribute__((aligned(16))) __bf16 Kb[2][64][36];
    __shared__ __attribute__((aligned(16))) __bf16 Vb[2][32][68];
    __shared__ __attribute__((aligned(16))) __bf16 Pm[4][16][68];
    int t = threadIdx.x, lane = t & 63, wv = t >> 6;
    int l15 = lane & 15, quad = lane >> 4;
    const __bf16* qbase = qk + (size_t)(b * S) * 256 + hh * 32;
    const __bf16* kbase = qk + (size_t)(b * S) * 256 + 128 + hh * 32;
    const __bf16* vbase = vt + ((size_t)(b * 4 + hh) * 32) * 1024;
    // scale * log2(e) * 2^23 (Schraudolph pre-scale)
    const float qscale = 0.1767766952966369f * 1.4426950408889634f * 8388608.0f;
    const float C2 = 1065101558.0f;   // (127<<23) - 0.03*2^23
    const f32x4 cinit = {C2, C2, C2, C2};
    bf16x8 vones;
#pragma unroll
    for (int j = 0; j < 8; ++j) vones[j] = (__bf16)1.0f;

    bf16x8 bQ;
    {
        bf16x8 qv = *(const bf16x8*)&qbase[(size_t)(qt * 64 + wv * 16 + l15) * 256 + quad * 8];
#pragma unroll
        for (int j = 0; j < 8; ++j) bQ[j] = (__bf16)((float)qv[j] * qscale);
    }

    int ksr = t >> 2, ksc = (t & 3) * 8;
    int vsr = t >> 3, vsc = (t & 7) * 8;

    {
        bf16x8 k0 = *(const bf16x8*)&kbase[(size_t)ksr * 256 + ksc];
        bf16x8 v0 = *(const bf16x8*)&vbase[(size_t)vsr * 1024 + vsc];
        st8(&Kb[0][ksr][ksc], k0);
        st8(&Vb[0][vsr][vsc], v0);
    }
    __syncthreads();

    f32x4 o0 = {0.f, 0.f, 0.f, 0.f}, o1 = {0.f, 0.f, 0.f, 0.f};
    f32x4 ol = {0.f, 0.f, 0.f, 0.f};

    for (int it = 0; it < 16; ++it) {
        const int cur = it & 1;
        bf16x8 knext, vnext;
        if (it < 15) {
            knext = *(const bf16x8*)&kbase[(size_t)((it + 1) * 64 + ksr) * 256 + ksc];
            vnext = *(const bf16x8*)&vbase[(size_t)vsr * 1024 + (it + 1) * 64 + vsc];
        }
        // scores + Schraudolph exp2 + pack to Pm
        f32x4 sf[4];
#pragma unroll
        for (int c = 0; c < 4; ++c) {
            bf16x8 aK = ld8(&Kb[cur][c * 16 + l15][quad * 8]);
            sf[c] = __builtin_amdgcn_mfma_f32_16x16x32_bf16(aK, bQ, cinit, 0, 0, 0);
        }
#pragma unroll
        for (int c = 0; c < 4; ++c) {
            int i0 = (int)sf[c][0];
            int i1 = (int)sf[c][1];
            int i2 = (int)sf[c][2];
            int i3 = (int)sf[c][3];
            uint2 u;
            u.x = __builtin_amdgcn_perm((unsigned)i1, (unsigned)i0, 0x07060302u);
            u.y = __builtin_amdgcn_perm((unsigned)i3, (unsigned)i2, 0x07060302u);
            *(uint2*)&Pm[wv][l15][c * 16 + quad * 4] = u;
        }
        __asm__ __volatile__("" ::: "memory");  // Pm writes before ap reads
        // PV + l via ones-MFMA
#pragma unroll
        for (int kc = 0; kc < 2; ++kc) {
            bf16x8 ap  = ld8(&Pm[wv][l15][kc * 32 + quad * 8]);
            bf16x8 bv0 = ld8(&Vb[cur][l15][kc * 32 + quad * 8]);
            bf16x8 bv1 = ld8(&Vb[cur][16 + l15][kc * 32 + quad * 8]);
            o0 = __builtin_amdgcn_mfma_f32_16x16x32_bf16(ap, bv0, o0, 0, 0, 0);
            o1 = __builtin_amdgcn_mfma_f32_16x16x32_bf16(ap, bv1, o1, 0, 0, 0);
            ol = __builtin_amdgcn_mfma_f32_16x16x32_bf16(ap, vones, ol, 0, 0, 0);
        }
        __asm__ __volatile__("" ::: "memory");  // ap reads before next Pm writes
        if (it < 15) {
            st8(&Kb[cur ^ 1][ksr][ksc], knext);
            st8(&Vb[cur ^ 1][vsr][vsc], vnext);
            __syncthreads();
        }
    }

#pragma unroll
    for (int reg = 0; reg < 4; ++reg) {
        float linv = 1.f / ol[reg];   // same C-layout row as o
        int row = qt * 64 + wv * 16 + quad * 4 + reg;
        __bf16* op = O + ((size_t)(b * S) + row) * E + hh * 32;
        op[l15] = (__bf16)(o0[reg] * linv);
        op[16 + l15] = (__bf16)(o1[reg] * linv);
    }
}

// ---------------- mega-fused: out-proj + res + LN1 + FFN1 + FFN2 + res + LN2 ----------------
__global__ __launch_bounds__(256) void k_layer2(const __bf16* __restrict__ t0b,
        const __bf16* __restrict__ Wo, const float* __restrict__ ob,
        const float* __restrict__ g1, const float* __restrict__ bt1,
        const __bf16* __restrict__ W1, const float* __restrict__ b1v,
        const __bf16* __restrict__ W2, const float* __restrict__ b2v,
        const float* __restrict__ g2, const float* __restrict__ bt2,
        __bf16* __restrict__ hb)
{
    __shared__ __attribute__((aligned(16))) __bf16 As[64][132];
    __shared__ __attribute__((aligned(16))) __bf16 Ws[128][132];
    __shared__ float red[2][64][2];
    int t = threadIdx.x;
    int m0 = blockIdx.x * 64;
    int arow = t >> 2, acol = (t & 3) * 32;
    int wrow = t >> 1, wcol = (t & 1) * 64;
    {
        const __bf16* Ap = t0b + (size_t)(m0 + arow) * 128 + acol;
#pragma unroll
        for (int j = 0; j < 4; ++j)
            st8(&As[arow][acol + j * 8], *(const bf16x8*)&Ap[j * 8]);
        const __bf16* Wp = Wo + (size_t)wrow * 128 + wcol;
#pragma unroll
        for (int j = 0; j < 8; ++j)
            st8(&Ws[wrow][wcol + j * 8], *(const bf16x8*)&Wp[j * 8]);
    }
    __syncthreads();
    int lane = t & 63, wv = t >> 6;
    int l15 = lane & 15, quad = lane >> 4;
    int nh = wv & 1, mh = wv >> 1;
    f32x4 acc[4][2];

    // ---------- phase A: out-proj ----------
#pragma unroll
    for (int i = 0; i < 4; ++i)
#pragma unroll
        for (int j = 0; j < 2; ++j) acc[i][j] = (f32x4){0.f, 0.f, 0.f, 0.f};
#pragma unroll
    for (int kc = 0; kc < 4; ++kc) {
        bf16x8 aw[4], ba[2];
#pragma unroll
        for (int nc = 0; nc < 4; ++nc)
            aw[nc] = ld8(&Ws[nh * 64 + nc * 16 + l15][kc * 32 + quad * 8]);
#pragma unroll
        for (int mc = 0; mc < 2; ++mc)
            ba[mc] = ld8(&As[mh * 32 + mc * 16 + l15][kc * 32 + quad * 8]);
#pragma unroll
        for (int nc = 0; nc < 4; ++nc)
#pragma unroll
            for (int mc = 0; mc < 2; ++mc)
                acc[nc][mc] = __builtin_amdgcn_mfma_f32_16x16x32_bf16(aw[nc], ba[mc], acc[nc][mc], 0, 0, 0);
    }
    float s1[2] = {0.f, 0.f}, s2[2] = {0.f, 0.f};
#pragma unroll
    for (int nc = 0; nc < 4; ++nc) {
        float4 bv = *(const float4*)&ob[nh * 64 + nc * 16 + quad * 4];
#pragma unroll
        for (int mc = 0; mc < 2; ++mc) {
            int m = m0 + mh * 32 + mc * 16 + l15;
            bf16x4 rv = *(const bf16x4*)&hb[(size_t)m * 128 + nh * 64 + nc * 16 + quad * 4];
            acc[nc][mc][0] += bv.x + (float)rv[0];
            acc[nc][mc][1] += bv.y + (float)rv[1];
            acc[nc][mc][2] += bv.z + (float)rv[2];
            acc[nc][mc][3] += bv.w + (float)rv[3];
#pragma unroll
            for (int i = 0; i < 4; ++i) {
                s1[mc] += acc[nc][mc][i];
                s2[mc] += acc[nc][mc][i] * acc[nc][mc][i];
            }
        }
    }
#pragma unroll
    for (int mc = 0; mc < 2; ++mc) {
        s1[mc] += __shfl_xor(s1[mc], 16); s1[mc] += __shfl_xor(s1[mc], 32);
        s2[mc] += __shfl_xor(s2[mc], 16); s2[mc] += __shfl_xor(s2[mc], 32);
    }
    if (quad == 0) {
#pragma unroll
        for (int mc = 0; mc < 2; ++mc) {
            red[nh][mh * 32 + mc * 16 + l15][0] = s1[mc];
            red[nh][mh * 32 + mc * 16 + l15][1] = s2[mc];
        }
    }
    __syncthreads();
    float mu[2], rs[2];
#pragma unroll
    for (int mc = 0; mc < 2; ++mc) {
        int r = mh * 32 + mc * 16 + l15;
        float S1 = red[0][r][0] + red[1][r][0];
        float S2 = red[0][r][1] + red[1][r][1];
        mu[mc] = S1 * (1.f / 128.f);
        float var = S2 * (1.f / 128.f) - mu[mc] * mu[mc];
        rs[mc] = rsqrtf(var + EPS);
    }
    bf16x4 res2[4][2];
#pragma unroll
    for (int nc = 0; nc < 4; ++nc) {
        float4 gv = *(const float4*)&g1[nh * 64 + nc * 16 + quad * 4];
        float4 bb = *(const float4*)&bt1[nh * 64 + nc * 16 + quad * 4];
#pragma unroll
        for (int mc = 0; mc < 2; ++mc) {
            float o0 = (acc[nc][mc][0] - mu[mc]) * rs[mc] * gv.x + bb.x;
            float o1 = (acc[nc][mc][1] - mu[mc]) * rs[mc] * gv.y + bb.y;
            float o2 = (acc[nc][mc][2] - mu[mc]) * rs[mc] * gv.z + bb.z;
            float o3 = (acc[nc][mc][3] - mu[mc]) * rs[mc] * gv.w + bb.w;
            bf16x4 xb;
            xb[0] = (__bf16)o0; xb[1] = (__bf16)o1;
            xb[2] = (__bf16)o2; xb[3] = (__bf16)o3;
            res2[nc][mc] = xb;
            *(bf16x4*)&As[mh * 32 + mc * 16 + l15][nh * 64 + nc * 16 + quad * 4] = xb;
        }
    }
    {
        const __bf16* Wp = W1 + (size_t)wrow * 128 + wcol;
#pragma unroll
        for (int j = 0; j < 8; ++j)
            st8(&Ws[wrow][wcol + j * 8], *(const bf16x8*)&Wp[j * 8]);
    }
    __syncthreads();

    // ---------- phase B: FFN1 ----------
#pragma unroll
    for (int i = 0; i < 4; ++i)
#pragma unroll
        for (int j = 0; j < 2; ++j) acc[i][j] = (f32x4){0.f, 0.f, 0.f, 0.f};
#pragma unroll
    for (int kc = 0; kc < 4; ++kc) {
        bf16x8 aw[4], ba[2];
#pragma unroll
        for (int nc = 0; nc < 4; ++nc)
            aw[nc] = ld8(&Ws[nh * 64 + nc * 16 + l15][kc * 32 + quad * 8]);
#pragma unroll
        for (int mc = 0; mc < 2; ++mc)
            ba[mc] = ld8(&As[mh * 32 + mc * 16 + l15][kc * 32 + quad * 8]);
#pragma unroll
        for (int nc = 0; nc < 4; ++nc)
#pragma unroll
            for (int mc = 0; mc < 2; ++mc)
                acc[nc][mc] = __builtin_amdgcn_mfma_f32_16x16x32_bf16(aw[nc], ba[mc], acc[nc][mc], 0, 0, 0);
    }
    __syncthreads();
#pragma unroll
    for (int nc = 0; nc < 4; ++nc) {
        float4 bv = *(const float4*)&b1v[nh * 64 + nc * 16 + quad * 4];
#pragma unroll
        for (int mc = 0; mc < 2; ++mc) {
            float v0 = fmaxf(acc[nc][mc][0] + bv.x, 0.f);
            float v1 = fmaxf(acc[nc][mc][1] + bv.y, 0.f);
            float v2 = fmaxf(acc[nc][mc][2] + bv.z, 0.f);
            float v3 = fmaxf(acc[nc][mc][3] + bv.w, 0.f);
            uint2 u; u.x = pk2(v0, v1); u.y = pk2(v2, v3);
            *(uint2*)&As[mh * 32 + mc * 16 + l15][nh * 64 + nc * 16 + quad * 4] = u;
        }
    }
    {
        const __bf16* Wp = W2 + (size_t)wrow * 128 + wcol;
#pragma unroll
        for (int j = 0; j < 8; ++j)
            st8(&Ws[wrow][wcol + j * 8], *(const bf16x8*)&Wp[j * 8]);
    }
    __syncthreads();

    // ---------- phase C: FFN2 + res2 + LN2 ----------
#pragma unroll
    for (int i = 0; i < 4; ++i)
#pragma unroll
        for (int j = 0; j < 2; ++j) acc[i][j] = (f32x4){0.f, 0.f, 0.f, 0.f};
#pragma unroll
    for (int kc = 0; kc < 4; ++kc) {
        bf16x8 aw[4], ba[2];
#pragma unroll
        for (int nc = 0; nc < 4; ++nc)
            aw[nc] = ld8(&Ws[nh * 64 + nc * 16 + l15][kc * 32 + quad * 8]);
#pragma unroll
        for (int mc = 0; mc < 2; ++mc)
            ba[mc] = ld8(&As[mh * 32 + mc * 16 + l15][kc * 32 + quad * 8]);
#pragma unroll
        for (int nc = 0; nc < 4; ++nc)
#pragma unroll
            for (int mc = 0; mc < 2; ++mc)
                acc[nc][mc] = __builtin_amdgcn_mfma_f32_16x16x32_bf16(aw[nc], ba[mc], acc[nc][mc], 0, 0, 0);
    }
    s1[0] = s1[1] = s2[0] = s2[1] = 0.f;
#pragma unroll
    for (int nc = 0; nc < 4; ++nc) {
        float4 bv = *(const float4*)&b2v[nh * 64 + nc * 16 + quad * 4];
#pragma unroll
        for (int mc = 0; mc < 2; ++mc) {
            acc[nc][mc][0] += bv.x + (float)res2[nc][mc][0];
            acc[nc][mc][1] += bv.y + (float)res2[nc][mc][1];
            acc[nc][mc][2] += bv.z + (float)res2[nc][mc][2];
            acc[nc][mc][3] += bv.w + (float)res2[nc][mc][3];
#pragma unroll
            for (int i = 0; i < 4; ++i) {
                s1[mc] += acc[nc][mc][i];
                s2[mc] += acc[nc][mc][i] * acc[nc][mc][i];
            }
        }
    }
#pragma unroll
    for (int mc = 0; mc < 2; ++mc) {
        s1[mc] += __shfl_xor(s1[mc], 16); s1[mc] += __shfl_xor(s1[mc], 32);
        s2[mc] += __shfl_xor(s2[mc], 16); s2[mc] += __shfl_xor(s2[mc], 32);
    }
    if (quad == 0) {
#pragma unroll
        for (int mc = 0; mc < 2; ++mc) {
            red[nh][mh * 32 + mc * 16 + l15][0] = s1[mc];
            red[nh][mh * 32 + mc * 16 + l15][1] = s2[mc];
        }
    }
    __syncthreads();
#pragma unroll
    for (int mc = 0; mc < 2; ++mc) {
        int r = mh * 32 + mc * 16 + l15;
        float S1 = red[0][r][0] + red[1][r][0];
        float S2 = red[0][r][1] + red[1][r][1];
        mu[mc] = S1 * (1.f / 128.f);
        float var = S2 * (1.f / 128.f) - mu[mc] * mu[mc];
        rs[mc] = rsqrtf(var + EPS);
    }
#pragma unroll
    for (int nc = 0; nc < 4; ++nc) {
        float4 gv = *(const float4*)&g2[nh * 64 + nc * 16 + quad * 4];
        float4 bb = *(const float4*)&bt2[nh * 64 + nc * 16 + quad * 4];
#pragma unroll
        for (int mc = 0; mc < 2; ++mc) {
            int m = m0 + mh * 32 + mc * 16 + l15;
            float o0 = (acc[nc][mc][0] - mu[mc]) * rs[mc] * gv.x + bb.x;
            float o1 = (acc[nc][mc][1] - mu[mc]) * rs[mc] * gv.y + bb.y;
            float o2 = (acc[nc][mc][2] - mu[mc]) * rs[mc] * gv.z + bb.z;
            float o3 = (acc[nc][mc][3] - mu[mc]) * rs[mc] * gv.w + bb.w;
            uint2 u; u.x = pk2(o0, o1); u.y = pk2(o2, o3);
            *(uint2*)&hb[(size_t)m * 128 + nh * 64 + nc * 16 + quad * 4] = u;
        }
    }
}

// ---------------- masked sum pool stage 1 (bf16 h) ----------------
__global__ __launch_bounds__(128) void k_pool1(const __bf16* __restrict__ h,
        const float* __restrict__ mask, float* __restrict__ part)
{
    int bx = blockIdx.x;
    int b = bx >> 3, ch = bx & 7, t = threadIdx.x;
    float acc = 0.f;
    const __bf16* hp = h + (size_t)(b * S + ch * 128) * E + t;
    const float* mp = mask + b * S + ch * 128;
    for (int s = 0; s < 128; ++s) acc += (float)hp[(size_t)s * E] * mp[s];
    part[(size_t)bx * E + t] = acc;
}

// ---------------- fused head: pool2 + cls1..3 + final sigmoid ----------------
__global__ __launch_bounds__(256) void k_head(const float* __restrict__ part,
        const float* __restrict__ cw1, const float* __restrict__ cb1,
        const float* __restrict__ cw2, const float* __restrict__ cb2,
        const float* __restrict__ cw3, const float* __restrict__ cb3,
        const float* __restrict__ cw4, const float* __restrict__ cb4,
        float* __restrict__ out)
{
    int b = blockIdx.x, t = threadIdx.x;
    __shared__ float p[128], za[256], zb[256];
    __shared__ float red4[4];
    if (t < 128) {
        float a = 0.f;
#pragma unroll
        for (int c = 0; c < 8; ++c) a += part[(size_t)(b * 8 + c) * 128 + t];
        p[t] = a;
    }
    __syncthreads();
    float a1 = cb1[t];
    for (int k = 0; k < 128; ++k) a1 += p[k] * cw1[t * 128 + k];
    za[t] = fmaxf(a1, 0.f);
    __syncthreads();
    float a2 = cb2[t];
    for (int k = 0; k < 256; ++k) a2 += za[k] * cw2[t * 256 + k];
    zb[t] = fmaxf(a2, 0.f);
    __syncthreads();
    float a3 = cb3[t];
    for (int k = 0; k < 256; ++k) a3 += zb[k] * cw3[t * 256 + k];
    float z3 = fmaxf(a3, 0.f);
    float prt = z3 * cw4[t];
#pragma unroll
    for (int o2 = 32; o2; o2 >>= 1) prt += __shfl_xor(prt, o2);
    if ((t & 63) == 0) red4[t >> 6] = prt;
    __syncthreads();
    if (t == 0) {
        float sum = red4[0] + red4[1] + red4[2] + red4[3] + cb4[0];
        out[b] = 1.f / (1.f + __expf(-sum));
    }
}

extern "C" void kernel_launch(void* const* d_in, const int* in_sizes, int n_in,
                              void* d_out, int out_size, void* d_ws, size_t ws_size,
                              hipStream_t stream)
{
    const float* x     = (const float*)d_in[0];
    const float* mask  = (const float*)d_in[1];
    const float* emb_w = (const float*)d_in[2];
    const float* emb_b = (const float*)d_in[3];
    const float* ipw   = (const float*)d_in[4];
    const float* ipb   = (const float*)d_in[5];
    const float* ow    = (const float*)d_in[6];
    const float* ob    = (const float*)d_in[7];
    const float* ln1g  = (const float*)d_in[8];
    const float* ln1b  = (const float*)d_in[9];
    const float* ln2g  = (const float*)d_in[10];
    const float* ln2b  = (const float*)d_in[11];
    const float* w1    = (const float*)d_in[12];
    const float* fb1   = (const float*)d_in[13];
    const float* w2    = (const float*)d_in[14];
    const float* fb2   = (const float*)d_in[15];
    const float* cw1   = (const float*)d_in[16];
    const float* cb1   = (const float*)d_in[17];
    const float* cw2   = (const float*)d_in[18];
    const float* cb2   = (const float*)d_in[19];
    const float* cw3   = (const float*)d_in[20];
    const float* cb3   = (const float*)d_in[21];
    const float* cw4   = (const float*)d_in[22];
    const float* cb4   = (const float*)d_in[23];

    char* p = (char*)d_ws;
    __bf16* hb   = (__bf16*)p;   p += (size_t)ROWS * E * 2;        // 8 MB bf16 stream
    __bf16* qkb  = (__bf16*)p;   p += (size_t)ROWS * 256 * 2;      // 16 MB Q|K rows
    __bf16* vtb  = (__bf16*)p;   p += (size_t)ROWS * 32 * 4 * 2 / 4; // 8 MB V^T [b,h,d,s]
    __bf16* t0b  = (__bf16*)p;   p += (size_t)ROWS * E * 2;        // 8 MB attn out
    __bf16* wb   = (__bf16*)p;   p += (size_t)(N_IPW + 3 * N_SQ) * 2;
    float* part  = (float*)p;    p += (size_t)B * 8 * E * 4;

    __bf16* wb_ipw = wb;
    __bf16* wb_ow  = wb + N_IPW;
    __bf16* wb_w1  = wb_ow + N_SQ;
    __bf16* wb_w2  = wb_w1 + N_SQ;

    k_embedcvt<<<NCVT + ROWS / 16, 256, 0, stream>>>(
        ipw, ow, w1, w2, wb, x, emb_w, emb_b, hb);
    for (int L = 0; L < 3; ++L) {
        k_gemm_qkv<<<dim3(6, ROWS / 128), 256, 0, stream>>>(
            hb, wb_ipw + (size_t)L * 384 * 128, ipb + L * 384, qkb, vtb);
        k_attn5<<<B * NH * (S / 64), 256, 0, stream>>>(qkb, vtb, t0b);
        k_layer2<<<ROWS / 64, 256, 0, stream>>>(
            t0b, wb_ow + (size_t)L * 128 * 128, ob + L * 128,
            ln1g + L * E, ln1b + L * E,
            wb_w1 + (size_t)L * 128 * 128, fb1 + L * 128,
            wb_w2 + (size_t)L * 128 * 128, fb2 + L * 128,
            ln2g + L * E, ln2b + L * E, hb);
    }
    k_pool1<<<B * 8, 128, 0, stream>>>(hb, mask, part);
    k_head<<<B, 256, 0, stream>>>(part, cw1, cb1, cw2, cb2, cw3, cb3, cw4, cb4,
                                  (float*)d_out);
}